// Round 1
// 137.482 us; speedup vs baseline: 1.5204x; 1.5204x over previous
//
#include <hip/hip_runtime.h>
#include <cstdint>
#include <cstddef>

// ---------------------------------------------------------------------------
// Gated attention (AlphaFold-style), MI355X / gfx950.
// B=32, Q=K=512, A=256, H=8, C=32, O=256.  All inputs fp32, output fp32.
// Internally bf16 MFMA (threshold is ~2% of max|ref| -> plenty of margin).
// R1: proj/outp operand-swap (vector epilogue stores) + Wlds double-buffer
//     (1 barrier/slice, load-latency overlap); attn per-qt bias loads
//     (halve forced bias liveness at the 128-VGPR cap).
// ---------------------------------------------------------------------------

typedef __attribute__((ext_vector_type(8))) short short8;   // 8 x bf16 (raw bits)
typedef __attribute__((ext_vector_type(4))) float f32x4;
typedef __attribute__((ext_vector_type(4))) unsigned int u32x4;
typedef __attribute__((ext_vector_type(2))) unsigned int u32x2;

#define DEVFN static __device__ __forceinline__
#define L2E 1.4426950408889634f

DEVFN unsigned short f2b(float f) {           // fp32 -> bf16 (RNE, finite inputs)
  unsigned int u = __builtin_bit_cast(unsigned int, f);
  u += 0x7fffu + ((u >> 16) & 1u);
  return (unsigned short)(u >> 16);
}
DEVFN float b2f(unsigned int bits16) {        // bf16 bits -> fp32
  return __builtin_bit_cast(float, bits16 << 16);
}
DEVFN unsigned int pack2(float a, float b) {  // two bf16 in one dword
  return (unsigned int)f2b(a) | ((unsigned int)f2b(b) << 16);
}
DEVFN f32x4 mfma16(short8 a, short8 b, f32x4 c) {
  return __builtin_amdgcn_mfma_f32_16x16x32_bf16(a, b, c, 0, 0, 0);
}
// MFMA 16x16x32 layouts (gfx950, per verified guide):
//  A: row = lane&15,           k = 8*(lane>>4)+j   (j=0..7)
//  B: col = lane&15,           k = 8*(lane>>4)+j
//  D: col = lane&15,           row = 4*(lane>>4)+r (r=0..3)

// ---------------------------------------------------------------------------
// Kernel 0: transpose 5 weight matrices [256][256] fp32 -> bf16 W^T [n][a]
// ---------------------------------------------------------------------------
__global__ __launch_bounds__(256) void wtrans_kernel(
    const float* __restrict__ qw, const float* __restrict__ kw,
    const float* __restrict__ vw, const float* __restrict__ gw,
    const float* __restrict__ ow,
    unsigned short* __restrict__ wtq, unsigned short* __restrict__ wtk,
    unsigned short* __restrict__ wtv, unsigned short* __restrict__ wtg,
    unsigned short* __restrict__ wt3)
{
  const int matid = blockIdx.x >> 4;
  const int tile  = blockIdx.x & 15;
  const float* src = (matid == 0) ? qw : (matid == 1) ? kw : (matid == 2) ? vw
                   : (matid == 3) ? gw : ow;
  unsigned short* dst = (matid == 0) ? wtq : (matid == 1) ? wtk : (matid == 2) ? wtv
                      : (matid == 3) ? wtg : wt3;
  const int tr = (tile >> 2) * 64, tc = (tile & 3) * 64;
  __shared__ unsigned short T[64 * 72];
  const int t = threadIdx.x;
  {
    const int row = t >> 2, cb = (t & 3) * 16;
#pragma unroll
    for (int ii = 0; ii < 4; ++ii) {
      f32x4 v = *(const f32x4*)&src[(size_t)(tr + row) * 256 + tc + cb + ii * 4];
      u32x2 p; p.x = pack2(v.x, v.y); p.y = pack2(v.z, v.w);
      *(u32x2*)&T[row * 72 + cb + ii * 4] = p;
    }
  }
  __syncthreads();
  {
    const int c0 = t >> 2, rb = (t & 3) * 16;
    unsigned short vals[16];
#pragma unroll
    for (int m = 0; m < 16; ++m) vals[m] = T[(rb + m) * 72 + c0];
    u32x4 s0, s1;
    s0.x = (unsigned)vals[0]  | ((unsigned)vals[1]  << 16);
    s0.y = (unsigned)vals[2]  | ((unsigned)vals[3]  << 16);
    s0.z = (unsigned)vals[4]  | ((unsigned)vals[5]  << 16);
    s0.w = (unsigned)vals[6]  | ((unsigned)vals[7]  << 16);
    s1.x = (unsigned)vals[8]  | ((unsigned)vals[9]  << 16);
    s1.y = (unsigned)vals[10] | ((unsigned)vals[11] << 16);
    s1.z = (unsigned)vals[12] | ((unsigned)vals[13] << 16);
    s1.w = (unsigned)vals[14] | ((unsigned)vals[15] << 16);
    unsigned short* dp = &dst[(size_t)(tc + c0) * 256 + tr + rb];
    *(u32x4*)dp = s0;
    *(u32x4*)(dp + 8) = s1;
  }
}

// ---------------------------------------------------------------------------
// Kernel 1: projections. blocks 0..255: q_data -> q(bf16,scaled) + gate(fp32)
//           blocks 256..511: m_data -> k(bf16) + v(bf16).
// Outputs laid out [B,H,S,C] (contiguous per (b,h) slice).
// Operand-swapped MFMA: A=W^T fragment (rows n), B=data fragment (cols q).
// D row = n = nt*16+4g+r -> lane holds 4 CONSECUTIVE channels of one row
// -> 8B/16B vector epilogue stores. Wlds double-buffered: ONE barrier per
// 32-wide W slice, global W load issued before compute (latency hidden).
// ---------------------------------------------------------------------------
__global__ __launch_bounds__(256, 2) void proj_kernel(
    const float* __restrict__ q_data, const float* __restrict__ m_data,
    const unsigned short* __restrict__ wtq, const unsigned short* __restrict__ wtk,
    const unsigned short* __restrict__ wtv, const unsigned short* __restrict__ wtg,
    const float* __restrict__ gating_b,
    unsigned short* __restrict__ qp, unsigned short* __restrict__ kp,
    unsigned short* __restrict__ vp, float* __restrict__ gate)
{
  const int bid = blockIdx.x;
  const bool mside = bid >= 256;
  const int r0 = (mside ? bid - 256 : bid) * 64;
  const float* inp = mside ? m_data : q_data;
  __shared__ unsigned short Alds[64 * 264];       // 64 rows x 256 a, pad 264
  __shared__ unsigned short Wlds[2][256 * 40];    // dbuf: 256 n x 32 a-slice
  const int t = threadIdx.x;
  const int lane = t & 63, wave = t >> 6;
  const int l15 = lane & 15, g = lane >> 4;

  { // stage A tile as bf16
    const int row = t >> 2, cb = (t & 3) * 64;
    const float* ip = &inp[(size_t)(r0 + row) * 256 + cb];
#pragma unroll
    for (int i = 0; i < 8; ++i) {
      f32x4 a0 = *(const f32x4*)&ip[i * 8];
      f32x4 a1 = *(const f32x4*)&ip[i * 8 + 4];
      u32x4 pk;
      pk.x = pack2(a0.x, a0.y); pk.y = pack2(a0.z, a0.w);
      pk.z = pack2(a1.x, a1.y); pk.w = pack2(a1.z, a1.w);
      *(u32x4*)&Alds[row * 264 + cb + i * 8] = pk;
    }
  }

  const unsigned short* wt0 = mside ? wtk : wtq;
  const unsigned short* wt1 = mside ? wtv : wtg;

  { // prologue: W slice 0 -> buf 0
    const u32x4* wsrc = (const u32x4*)&wt0[(size_t)t * 256];
    u32x4 a = wsrc[0], b = wsrc[1], c = wsrc[2], d = wsrc[3];
    *(u32x4*)&Wlds[0][t * 40 + 0]  = a;
    *(u32x4*)&Wlds[0][t * 40 + 8]  = b;
    *(u32x4*)&Wlds[0][t * 40 + 16] = c;
    *(u32x4*)&Wlds[0][t * 40 + 24] = d;
  }

  f32x4 acc[16];
#pragma unroll
  for (int nt = 0; nt < 16; ++nt) acc[nt] = f32x4{0.f, 0.f, 0.f, 0.f};

  const int arow = (wave * 16 + l15) * 264 + 8 * g;
  const int grow = r0 + wave * 16 + l15;          // B-col -> data row (b*512+q)
  const int ob = grow >> 9, oq = grow & 511;

#pragma unroll
  for (int s = 0; s < 16; ++s) {                  // s = oi*8 + ks
    const int p = s & 1;
    __syncthreads();                               // buf p ready; buf p^1 free
    u32x4 nw0, nw1, nw2, nw3;
    if (s < 15) {                                  // issue next-slice W load
      const unsigned short* wt = (s + 1 < 8) ? wt0 : wt1;
      const u32x4* wsrc = (const u32x4*)&wt[(size_t)t * 256 + ((s + 1) & 7) * 32];
      nw0 = wsrc[0]; nw1 = wsrc[1]; nw2 = wsrc[2]; nw3 = wsrc[3];
    }
    const int ks = s & 7;
    short8 bf = __builtin_bit_cast(short8, *(const u32x4*)&Alds[arow + ks * 32]);
#pragma unroll
    for (int nt = 0; nt < 16; ++nt) {
      short8 wf = __builtin_bit_cast(short8,
          *(const u32x4*)&Wlds[p][(nt * 16 + l15) * 40 + 8 * g]);
      acc[nt] = mfma16(wf, bf, acc[nt]);           // D: row=n(4g+r), col=q(l15)
    }
    if (s < 15) {
      *(u32x4*)&Wlds[p ^ 1][t * 40 + 0]  = nw0;
      *(u32x4*)&Wlds[p ^ 1][t * 40 + 8]  = nw1;
      *(u32x4*)&Wlds[p ^ 1][t * 40 + 16] = nw2;
      *(u32x4*)&Wlds[p ^ 1][t * 40 + 24] = nw3;
    }
    if (s == 7 || s == 15) {                       // epilogue per oi
      const int oi = s >> 3;
#pragma unroll
      for (int nt = 0; nt < 16; ++nt) {
        const int n0 = nt * 16 + 4 * g;            // 4 consecutive n per lane
        const int h = n0 >> 5, c0 = n0 & 31;
        const size_t idx = ((size_t)(ob * 8 + h) * 512 + oq) * 32 + c0;
        f32x4 v = acc[nt];
        if (!mside) {
          if (oi == 0) {
            u32x2 st;
            st.x = pack2(v.x * 0.17677669529663687f, v.y * 0.17677669529663687f);
            st.y = pack2(v.z * 0.17677669529663687f, v.w * 0.17677669529663687f);
            *(u32x2*)&qp[idx] = st;
          } else {
            f32x4 gb = *(const f32x4*)&gating_b[n0];
            f32x4 gv;
            gv.x = 1.0f / (1.0f + exp2f(-(v.x + gb.x) * L2E));
            gv.y = 1.0f / (1.0f + exp2f(-(v.y + gb.y) * L2E));
            gv.z = 1.0f / (1.0f + exp2f(-(v.z + gb.z) * L2E));
            gv.w = 1.0f / (1.0f + exp2f(-(v.w + gb.w) * L2E));
            *(f32x4*)&gate[idx] = gv;
          }
        } else {
          u32x2 st;
          st.x = pack2(v.x, v.y); st.y = pack2(v.z, v.w);
          if (oi == 0) *(u32x2*)&kp[idx] = st;
          else         *(u32x2*)&vp[idx] = st;
        }
        acc[nt] = f32x4{0.f, 0.f, 0.f, 0.f};
      }
    }
  }
}

// ---------------------------------------------------------------------------
// Kernel 2: fused attention, 1 block per (b, h, q-half), 8 waves x 32 q-rows.
// Swapped QK^T (S^T = K.Q^T) so D-fragments hold 4 CONSECUTIVE k per lane ->
// bias streams load as coalesced float4. NO online max: logits are bounded
// (~|16| worst case; exp2 fits fp32 easily; bf16 precision is scale-free),
// so p = exp2(s*log2e) directly, l just accumulates. PV via shfl_xor(16)
// reassembly with k-slot permutation pi = [0,16,8,24] absorbed into V reads.
// grid=512 -> 2 blocks/CU (146KB LDS), 4 waves/SIMD for latency hiding.
// R1: bias loads moved inside qt loop -> peak bias liveness 16 regs not 32
// (we sit at the 128-VGPR cap from __launch_bounds__(512,4)).
// ---------------------------------------------------------------------------
__global__ __launch_bounds__(512, 4) void attn_kernel(
    const unsigned short* __restrict__ qp, const unsigned short* __restrict__ kp,
    const unsigned short* __restrict__ vp,
    const float* __restrict__ bias, const float* __restrict__ nbias,
    const float* __restrict__ bbias,
    unsigned short* __restrict__ wa)
{
  const int bid = blockIdx.x;
  const int h = bid & 7;                    // same-h blocks share an XCD -> nbias L2-hot
  const int qh = (bid >> 3) & 1;
  const int b = bid >> 4;
  const int bh = b * 8 + h;
  const int t = threadIdx.x;
  const int lane = t & 63, wave = t >> 6;
  const int l15 = lane & 15, g = lane >> 4;

  __shared__ unsigned short Klds[512 * 40];  // [k][c], pad 40 (2-way only)
  __shared__ unsigned short Vt[32 * 520];    // V^T [c][k], pad 520

  { // stage K rows + transposed V (512 threads, one k-row each)
    const int row = t;
    const u32x4* ks = (const u32x4*)&kp[((size_t)bh * 512 + row) * 32];
    u32x4 k0 = ks[0], k1 = ks[1], k2 = ks[2], k3 = ks[3];
    *(u32x4*)&Klds[row * 40 + 0]  = k0;
    *(u32x4*)&Klds[row * 40 + 8]  = k1;
    *(u32x4*)&Klds[row * 40 + 16] = k2;
    *(u32x4*)&Klds[row * 40 + 24] = k3;
    const u32x4* vs = (const u32x4*)&vp[((size_t)bh * 512 + row) * 32];
#pragma unroll
    for (int cc = 0; cc < 4; ++cc) {
      u32x4 vv = vs[cc];
      unsigned int dw0 = vv.x, dw1 = vv.y, dw2 = vv.z, dw3 = vv.w;
      const int c = cc * 8;
      Vt[(c + 0) * 520 + row] = (unsigned short)(dw0 & 0xffff);
      Vt[(c + 1) * 520 + row] = (unsigned short)(dw0 >> 16);
      Vt[(c + 2) * 520 + row] = (unsigned short)(dw1 & 0xffff);
      Vt[(c + 3) * 520 + row] = (unsigned short)(dw1 >> 16);
      Vt[(c + 4) * 520 + row] = (unsigned short)(dw2 & 0xffff);
      Vt[(c + 5) * 520 + row] = (unsigned short)(dw2 >> 16);
      Vt[(c + 6) * 520 + row] = (unsigned short)(dw3 & 0xffff);
      Vt[(c + 7) * 520 + row] = (unsigned short)(dw3 >> 16);
    }
  }

  const int qbase = qh * 256 + wave * 32;
  short8 qf[2];                              // Q as B-operand: col q=l15, c=8g+j
#pragma unroll
  for (int qt = 0; qt < 2; ++qt)
    qf[qt] = __builtin_bit_cast(short8,
        *(const u32x4*)&qp[((size_t)bh * 512 + qbase + qt * 16 + l15) * 32 + 8 * g]);

  const float* bbp = bbias + (size_t)bh * 512 * 512;
  const float* nbp = nbias + (size_t)h * 512 * 512;
  const float* bkp = bias + (size_t)b * 512;

  f32x4 acc[2][2];
#pragma unroll
  for (int ct = 0; ct < 2; ++ct)
#pragma unroll
    for (int qt = 0; qt < 2; ++qt) acc[ct][qt] = f32x4{0.f, 0.f, 0.f, 0.f};
  float l_r[2] = {0.f, 0.f};

  __syncthreads();

  const int pib = ((g & 1) << 4) | ((g >> 1) << 3);  // pi = [0,16,8,24]
  const bool godd = (g & 1) != 0;

  for (int kt = 0; kt < 16; ++kt) {
    const int k0 = kt * 32;
    short8 kf0 = __builtin_bit_cast(short8, *(const u32x4*)&Klds[(k0 + l15) * 40 + 8 * g]);
    short8 kf1 = __builtin_bit_cast(short8, *(const u32x4*)&Klds[(k0 + 16 + l15) * 40 + 8 * g]);
    short8 vf0 = __builtin_bit_cast(short8, *(const u32x4*)&Vt[l15 * 520 + k0 + pib]);
    short8 vf1 = __builtin_bit_cast(short8, *(const u32x4*)&Vt[(16 + l15) * 520 + k0 + pib]);
    f32x4 bk0 = *(const f32x4*)&bkp[k0 + 4 * g];
    f32x4 bk1 = *(const f32x4*)&bkp[k0 + 16 + 4 * g];
#pragma unroll
    for (int qt = 0; qt < 2; ++qt) {
      const int q = qbase + qt * 16 + l15;
      const float* bq = &bbp[(size_t)q * 512 + k0 + 4 * g];
      const float* nq = &nbp[(size_t)q * 512 + k0 + 4 * g];
      f32x4 bb0 = *(const f32x4*)bq;
      f32x4 bb1 = *(const f32x4*)(bq + 16);
      f32x4 nb0 = *(const f32x4*)nq;
      f32x4 nb1 = *(const f32x4*)(nq + 16);
      const f32x4 z = {0.f, 0.f, 0.f, 0.f};
      f32x4 s0 = mfma16(kf0, qf[qt], z);     // S^T: row k=4g+r, col q=l15
      f32x4 s1 = mfma16(kf1, qf[qt], z);
      s0 = s0 + bb0 + nb0 + bk0;
      s1 = s1 + bb1 + nb1 + bk1;
      f32x4 p0, p1;                          // no max subtraction (bounded logits)
      p0.x = exp2f(s0.x * L2E); p0.y = exp2f(s0.y * L2E);
      p0.z = exp2f(s0.z * L2E); p0.w = exp2f(s0.w * L2E);
      p1.x = exp2f(s1.x * L2E); p1.y = exp2f(s1.y * L2E);
      p1.z = exp2f(s1.z * L2E); p1.w = exp2f(s1.w * L2E);
      float sum8 = (p0.x + p0.y) + (p0.z + p0.w) + (p1.x + p1.y) + (p1.z + p1.w);
      sum8 += __shfl_xor(sum8, 16, 64);
      sum8 += __shfl_xor(sum8, 32, 64);
      l_r[qt] += sum8;
      // assemble P^T B-fragment (col q=l15, k-slots permuted by pi)
      unsigned int d0 = pack2(p0.x, p0.y), d1 = pack2(p0.z, p0.w);
      unsigned int e0 = pack2(p1.x, p1.y), e1 = pack2(p1.z, p1.w);
      unsigned int pd0 = __shfl_xor(d0, 16, 64), pd1 = __shfl_xor(d1, 16, 64);
      unsigned int pe0 = __shfl_xor(e0, 16, 64), pe1 = __shfl_xor(e1, 16, 64);
      u32x4 pfu;
      pfu.x = godd ? pe0 : d0;
      pfu.y = godd ? pe1 : d1;
      pfu.z = godd ? e0 : pd0;
      pfu.w = godd ? e1 : pd1;
      short8 pf = __builtin_bit_cast(short8, pfu);
      acc[0][qt] = mfma16(vf0, pf, acc[0][qt]);   // wa^T: row c, col q
      acc[1][qt] = mfma16(vf1, pf, acc[1][qt]);
    }
  }

  // epilogue: wa[b,h,q,c] bf16; lane holds c = ct*16+4g+r (contiguous 4)
  unsigned short* wab = wa + (size_t)bh * 512 * 32;
#pragma unroll
  for (int qt = 0; qt < 2; ++qt) {
    const float rl = 1.0f / l_r[qt];
    const int q = qbase + qt * 16 + l15;
#pragma unroll
    for (int ct = 0; ct < 2; ++ct) {
      f32x4 v = acc[ct][qt];
      u32x2 st;
      st.x = pack2(v.x * rl, v.y * rl);
      st.y = pack2(v.z * rl, v.w * rl);
      *(u32x2*)&wab[q * 32 + ct * 16 + 4 * g] = st;
    }
  }
}

// ---------------------------------------------------------------------------
// Kernel 3: out[b,q,o] = sum_hc wa*gate * W3[hc][o] + output_b[o]
// Operand-swapped: A=W3 fragment (rows o), B=activation (cols q) ->
// lane holds 4 consecutive o -> 16B f32x4 stores. Wlds double-buffered,
// activation (wa/gate) loads for slice s+1 issued during slice s compute.
// ---------------------------------------------------------------------------
__global__ __launch_bounds__(256, 2) void outp_kernel(
    const unsigned short* __restrict__ wa, const float* __restrict__ gate,
    const unsigned short* __restrict__ wt3, const float* __restrict__ out_b,
    float* __restrict__ out)
{
  const int r0 = blockIdx.x * 64;
  const int t = threadIdx.x;
  const int lane = t & 63, wave = t >> 6;
  const int l15 = lane & 15, g = lane >> 4;
  __shared__ unsigned short Wlds[2][256 * 40];

  const int grow = r0 + wave * 16 + l15;     // B-col -> data row (b*512+q)
  const int b = grow >> 9, q = grow & 511;

  { // prologue: W3 slice 0 -> buf 0
    const u32x4* wsrc = (const u32x4*)&wt3[(size_t)t * 256];
    u32x4 a = wsrc[0], bb = wsrc[1], c = wsrc[2], d = wsrc[3];
    *(u32x4*)&Wlds[0][t * 40 + 0]  = a;
    *(u32x4*)&Wlds[0][t * 40 + 8]  = bb;
    *(u32x4*)&Wlds[0][t * 40 + 16] = c;
    *(u32x4*)&Wlds[0][t * 40 + 24] = d;
  }
  // prologue: activation slice 0 (h = 0)
  size_t aidx = ((size_t)(b * 8 + 0) * 512 + q) * 32 + 8 * g;
  u32x4 cwv = *(const u32x4*)&wa[aidx];
  f32x4 cg0 = *(const f32x4*)&gate[aidx];
  f32x4 cg1 = *(const f32x4*)&gate[aidx + 4];

  f32x4 acc[16];
#pragma unroll
  for (int nt = 0; nt < 16; ++nt) acc[nt] = f32x4{0.f, 0.f, 0.f, 0.f};

#pragma unroll
  for (int s = 0; s < 8; ++s) {              // slice s: h = s, c = 8g..8g+7
    const int p = s & 1;
    __syncthreads();
    u32x4 nw0, nw1, nw2, nw3, nwv;
    f32x4 ng0, ng1;
    if (s < 7) {
      const u32x4* wsrc = (const u32x4*)&wt3[(size_t)t * 256 + (s + 1) * 32];
      nw0 = wsrc[0]; nw1 = wsrc[1]; nw2 = wsrc[2]; nw3 = wsrc[3];
      const size_t na = ((size_t)(b * 8 + s + 1) * 512 + q) * 32 + 8 * g;
      nwv = *(const u32x4*)&wa[na];
      ng0 = *(const f32x4*)&gate[na];
      ng1 = *(const f32x4*)&gate[na + 4];
    }
    // build gated-activation B-fragment from current regs
    float f0 = b2f(cwv.x & 0xffff) * cg0.x, f1 = b2f(cwv.x >> 16) * cg0.y;
    float f2 = b2f(cwv.y & 0xffff) * cg0.z, f3 = b2f(cwv.y >> 16) * cg0.w;
    float f4 = b2f(cwv.z & 0xffff) * cg1.x, f5 = b2f(cwv.z >> 16) * cg1.y;
    float f6 = b2f(cwv.w & 0xffff) * cg1.z, f7 = b2f(cwv.w >> 16) * cg1.w;
    u32x4 au;
    au.x = pack2(f0, f1); au.y = pack2(f2, f3);
    au.z = pack2(f4, f5); au.w = pack2(f6, f7);
    short8 af = __builtin_bit_cast(short8, au);
#pragma unroll
    for (int nt = 0; nt < 16; ++nt) {
      short8 wf = __builtin_bit_cast(short8,
          *(const u32x4*)&Wlds[p][(nt * 16 + l15) * 40 + 8 * g]);
      acc[nt] = mfma16(wf, af, acc[nt]);     // D: row=o(4g+r), col=q(l15)
    }
    if (s < 7) {
      *(u32x4*)&Wlds[p ^ 1][t * 40 + 0]  = nw0;
      *(u32x4*)&Wlds[p ^ 1][t * 40 + 8]  = nw1;
      *(u32x4*)&Wlds[p ^ 1][t * 40 + 16] = nw2;
      *(u32x4*)&Wlds[p ^ 1][t * 40 + 24] = nw3;
      cwv = nwv; cg0 = ng0; cg1 = ng1;
    }
  }
#pragma unroll
  for (int nt = 0; nt < 16; ++nt) {
    const int o0 = nt * 16 + 4 * g;          // 4 consecutive o per lane
    f32x4 ob4 = *(const f32x4*)&out_b[o0];
    f32x4 v = acc[nt] + ob4;
    *(f32x4*)&out[(size_t)grow * 256 + o0] = v;
  }
}

// ---------------------------------------------------------------------------
extern "C" void kernel_launch(void* const* d_in, const int* in_sizes, int n_in,
                              void* d_out, int out_size, void* d_ws, size_t ws_size,
                              hipStream_t stream)
{
  const float* q_data   = (const float*)d_in[0];
  const float* m_data   = (const float*)d_in[1];
  const float* bias     = (const float*)d_in[2];
  const float* nbb      = (const float*)d_in[3];
  const float* bbb      = (const float*)d_in[4];
  const float* query_w  = (const float*)d_in[5];
  const float* key_w    = (const float*)d_in[6];
  const float* value_w  = (const float*)d_in[7];
  const float* gating_w = (const float*)d_in[8];
  const float* gating_b = (const float*)d_in[9];
  const float* output_w = (const float*)d_in[10];
  const float* output_b = (const float*)d_in[11];
  float* out = (float*)d_out;

  const size_t QP_B   = (size_t)32 * 8 * 512 * 32 * 2;  // 8 MiB bf16 [B,H,S,C]
  const size_t GATE_B = (size_t)32 * 8 * 512 * 32 * 4;  // 16 MiB fp32
  const size_t WT_B   = (size_t)256 * 256 * 2;

  char* ws = (char*)d_ws;
  unsigned short* qp  = (unsigned short*)(ws);
  unsigned short* kp  = (unsigned short*)(ws + QP_B);
  unsigned short* vp  = (unsigned short*)(ws + 2 * QP_B);
  unsigned short* wab = (unsigned short*)(ws + 3 * QP_B);
  float*          gat = (float*)(ws + 4 * QP_B);
  unsigned short* wtq = (unsigned short*)(ws + 4 * QP_B + GATE_B);
  unsigned short* wtk = (unsigned short*)(ws + 4 * QP_B + GATE_B + WT_B);
  unsigned short* wtv = (unsigned short*)(ws + 4 * QP_B + GATE_B + 2 * WT_B);
  unsigned short* wtg = (unsigned short*)(ws + 4 * QP_B + GATE_B + 3 * WT_B);
  unsigned short* wt3 = (unsigned short*)(ws + 4 * QP_B + GATE_B + 4 * WT_B);
  const size_t need = 4 * QP_B + GATE_B + 5 * WT_B;
  if (ws_size < need) return;  // fail loudly (out stays poisoned)

  hipLaunchKernelGGL(wtrans_kernel, dim3(80), dim3(256), 0, stream,
                     query_w, key_w, value_w, gating_w, output_w,
                     wtq, wtk, wtv, wtg, wt3);
  hipLaunchKernelGGL(proj_kernel, dim3(512), dim3(256), 0, stream,
                     q_data, m_data, wtq, wtk, wtv, wtg, gating_b,
                     qp, kp, vp, gat);
  hipLaunchKernelGGL(attn_kernel, dim3(512), dim3(512), 0, stream,
                     qp, kp, vp, bias, nbb, bbb, wab);
  hipLaunchKernelGGL(outp_kernel, dim3(256), dim3(256), 0, stream,
                     wab, gat, wt3, output_b, out);
}

// Round 2
// 135.721 us; speedup vs baseline: 1.5401x; 1.0130x over previous
//
#include <hip/hip_runtime.h>
#include <cstdint>
#include <cstddef>

// ---------------------------------------------------------------------------
// Gated attention (AlphaFold-style), MI355X / gfx950.
// B=32, Q=K=512, A=256, H=8, C=32, O=256.  All inputs fp32, output fp32.
// Internally bf16 MFMA (threshold is ~2% of max|ref| -> plenty of margin).
// R2: proj 512-thr (4 waves/SIMD, n-split), outp 32-row blocks (2 blk/CU),
//     gate stored bf16 (-17 MB traffic), attn bias folded into MFMA C-op.
// ---------------------------------------------------------------------------

typedef __attribute__((ext_vector_type(8))) short short8;   // 8 x bf16 (raw bits)
typedef __attribute__((ext_vector_type(4))) float f32x4;
typedef __attribute__((ext_vector_type(4))) unsigned int u32x4;
typedef __attribute__((ext_vector_type(2))) unsigned int u32x2;

#define DEVFN static __device__ __forceinline__
#define L2E 1.4426950408889634f

DEVFN unsigned short f2b(float f) {           // fp32 -> bf16 (RNE, finite inputs)
  unsigned int u = __builtin_bit_cast(unsigned int, f);
  u += 0x7fffu + ((u >> 16) & 1u);
  return (unsigned short)(u >> 16);
}
DEVFN float b2f(unsigned int bits16) {        // bf16 bits -> fp32
  return __builtin_bit_cast(float, bits16 << 16);
}
DEVFN unsigned int pack2(float a, float b) {  // two bf16 in one dword
  return (unsigned int)f2b(a) | ((unsigned int)f2b(b) << 16);
}
DEVFN f32x4 mfma16(short8 a, short8 b, f32x4 c) {
  return __builtin_amdgcn_mfma_f32_16x16x32_bf16(a, b, c, 0, 0, 0);
}
// MFMA 16x16x32 layouts (gfx950, per verified guide):
//  A: row = lane&15,           k = 8*(lane>>4)+j   (j=0..7)
//  B: col = lane&15,           k = 8*(lane>>4)+j
//  D: col = lane&15,           row = 4*(lane>>4)+r (r=0..3)

// ---------------------------------------------------------------------------
// Kernel 0: transpose 5 weight matrices [256][256] fp32 -> bf16 W^T [n][a]
// ---------------------------------------------------------------------------
__global__ __launch_bounds__(256) void wtrans_kernel(
    const float* __restrict__ qw, const float* __restrict__ kw,
    const float* __restrict__ vw, const float* __restrict__ gw,
    const float* __restrict__ ow,
    unsigned short* __restrict__ wtq, unsigned short* __restrict__ wtk,
    unsigned short* __restrict__ wtv, unsigned short* __restrict__ wtg,
    unsigned short* __restrict__ wt3)
{
  const int matid = blockIdx.x >> 4;
  const int tile  = blockIdx.x & 15;
  const float* src = (matid == 0) ? qw : (matid == 1) ? kw : (matid == 2) ? vw
                   : (matid == 3) ? gw : ow;
  unsigned short* dst = (matid == 0) ? wtq : (matid == 1) ? wtk : (matid == 2) ? wtv
                      : (matid == 3) ? wtg : wt3;
  const int tr = (tile >> 2) * 64, tc = (tile & 3) * 64;
  __shared__ unsigned short T[64 * 72];
  const int t = threadIdx.x;
  {
    const int row = t >> 2, cb = (t & 3) * 16;
#pragma unroll
    for (int ii = 0; ii < 4; ++ii) {
      f32x4 v = *(const f32x4*)&src[(size_t)(tr + row) * 256 + tc + cb + ii * 4];
      u32x2 p; p.x = pack2(v.x, v.y); p.y = pack2(v.z, v.w);
      *(u32x2*)&T[row * 72 + cb + ii * 4] = p;
    }
  }
  __syncthreads();
  {
    const int c0 = t >> 2, rb = (t & 3) * 16;
    unsigned short vals[16];
#pragma unroll
    for (int m = 0; m < 16; ++m) vals[m] = T[(rb + m) * 72 + c0];
    u32x4 s0, s1;
    s0.x = (unsigned)vals[0]  | ((unsigned)vals[1]  << 16);
    s0.y = (unsigned)vals[2]  | ((unsigned)vals[3]  << 16);
    s0.z = (unsigned)vals[4]  | ((unsigned)vals[5]  << 16);
    s0.w = (unsigned)vals[6]  | ((unsigned)vals[7]  << 16);
    s1.x = (unsigned)vals[8]  | ((unsigned)vals[9]  << 16);
    s1.y = (unsigned)vals[10] | ((unsigned)vals[11] << 16);
    s1.z = (unsigned)vals[12] | ((unsigned)vals[13] << 16);
    s1.w = (unsigned)vals[14] | ((unsigned)vals[15] << 16);
    unsigned short* dp = &dst[(size_t)(tc + c0) * 256 + tr + rb];
    *(u32x4*)dp = s0;
    *(u32x4*)(dp + 8) = s1;
  }
}

// ---------------------------------------------------------------------------
// Kernel 1: projections. blocks 0..255: q_data -> q(bf16,scaled) + gate(bf16)
//           blocks 256..511: m_data -> k(bf16) + v(bf16).
// Outputs laid out [B,H,S,C] (contiguous per (b,h) slice).
// R2: 512 threads = 8 waves; wave = (stripe 0..3 = 16 rows) x (nhalf = 128 n).
// 4 waves/SIMD (2 blocks/CU) for latency hiding; acc[8] = 32 VGPRs/wave.
// Wlds double-buffered, one barrier/slice, W prefetched to regs pre-barrier.
// ---------------------------------------------------------------------------
__global__ __launch_bounds__(512, 4) void proj_kernel(
    const float* __restrict__ q_data, const float* __restrict__ m_data,
    const unsigned short* __restrict__ wtq, const unsigned short* __restrict__ wtk,
    const unsigned short* __restrict__ wtv, const unsigned short* __restrict__ wtg,
    const float* __restrict__ gating_b,
    unsigned short* __restrict__ qp, unsigned short* __restrict__ kp,
    unsigned short* __restrict__ vp, unsigned short* __restrict__ gate)
{
  const int bid = blockIdx.x;
  const bool mside = bid >= 256;
  const int r0 = (mside ? bid - 256 : bid) * 64;
  const float* inp = mside ? m_data : q_data;
  __shared__ unsigned short Alds[64 * 264];       // 64 rows x 256 a, pad 264
  __shared__ unsigned short Wlds[2][256 * 40];    // dbuf: 256 n x 32 a-slice
  const int t = threadIdx.x;
  const int lane = t & 63, wave = t >> 6;
  const int l15 = lane & 15, g = lane >> 4;
  const int stripe = wave & 3, nhalf = wave >> 2;

  { // stage A tile as bf16: 512 threads x 32 floats
    const int row = t >> 3, cb = (t & 7) * 32;
    const float* ip = &inp[(size_t)(r0 + row) * 256 + cb];
#pragma unroll
    for (int i = 0; i < 4; ++i) {
      f32x4 a0 = *(const f32x4*)&ip[i * 8];
      f32x4 a1 = *(const f32x4*)&ip[i * 8 + 4];
      u32x4 pk;
      pk.x = pack2(a0.x, a0.y); pk.y = pack2(a0.z, a0.w);
      pk.z = pack2(a1.x, a1.y); pk.w = pack2(a1.z, a1.w);
      *(u32x4*)&Alds[row * 264 + cb + i * 8] = pk;
    }
  }

  const unsigned short* wt0 = mside ? wtk : wtq;
  const unsigned short* wt1 = mside ? wtv : wtg;
  const int wrow = t & 255, whalf = t >> 8;       // W staging: 2 threads/row

  { // prologue: W slice 0 -> buf 0
    const u32x4* wsrc = (const u32x4*)&wt0[(size_t)wrow * 256 + whalf * 16];
    u32x4 a = wsrc[0], b = wsrc[1];
    *(u32x4*)&Wlds[0][wrow * 40 + whalf * 16 + 0] = a;
    *(u32x4*)&Wlds[0][wrow * 40 + whalf * 16 + 8] = b;
  }

  f32x4 acc[8];
#pragma unroll
  for (int j = 0; j < 8; ++j) acc[j] = f32x4{0.f, 0.f, 0.f, 0.f};

  const int arow = (stripe * 16 + l15) * 264 + 8 * g;
  const int grow = r0 + stripe * 16 + l15;        // B-col -> data row (b*512+q)
  const int ob = grow >> 9, oq = grow & 511;

#pragma unroll
  for (int s = 0; s < 16; ++s) {                  // s = oi*8 + ks
    const int p = s & 1;
    __syncthreads();                               // buf p ready; buf p^1 free
    u32x4 nw0, nw1;
    if (s < 15) {                                  // issue next-slice W load
      const unsigned short* wt = (s + 1 < 8) ? wt0 : wt1;
      const u32x4* wsrc =
          (const u32x4*)&wt[(size_t)wrow * 256 + ((s + 1) & 7) * 32 + whalf * 16];
      nw0 = wsrc[0]; nw1 = wsrc[1];
    }
    const int ks = s & 7;
    short8 bf = __builtin_bit_cast(short8, *(const u32x4*)&Alds[arow + ks * 32]);
#pragma unroll
    for (int j = 0; j < 8; ++j) {
      short8 wf = __builtin_bit_cast(short8,
          *(const u32x4*)&Wlds[p][((nhalf * 8 + j) * 16 + l15) * 40 + 8 * g]);
      acc[j] = mfma16(wf, bf, acc[j]);             // D: row=n(4g+r), col=q(l15)
    }
    if (s < 15) {
      *(u32x4*)&Wlds[p ^ 1][wrow * 40 + whalf * 16 + 0] = nw0;
      *(u32x4*)&Wlds[p ^ 1][wrow * 40 + whalf * 16 + 8] = nw1;
    }
    if (s == 7 || s == 15) {                       // epilogue per oi
      const int oi = s >> 3;
#pragma unroll
      for (int j = 0; j < 8; ++j) {
        const int n0 = (nhalf * 8 + j) * 16 + 4 * g;  // 4 consecutive n / lane
        const int h = n0 >> 5, c0 = n0 & 31;
        const size_t idx = ((size_t)(ob * 8 + h) * 512 + oq) * 32 + c0;
        f32x4 v = acc[j];
        if (!mside) {
          if (oi == 0) {
            u32x2 st;
            st.x = pack2(v.x * 0.17677669529663687f, v.y * 0.17677669529663687f);
            st.y = pack2(v.z * 0.17677669529663687f, v.w * 0.17677669529663687f);
            *(u32x2*)&qp[idx] = st;
          } else {
            f32x4 gb = *(const f32x4*)&gating_b[n0];
            f32x4 gv;
            gv.x = 1.0f / (1.0f + exp2f(-(v.x + gb.x) * L2E));
            gv.y = 1.0f / (1.0f + exp2f(-(v.y + gb.y) * L2E));
            gv.z = 1.0f / (1.0f + exp2f(-(v.z + gb.z) * L2E));
            gv.w = 1.0f / (1.0f + exp2f(-(v.w + gb.w) * L2E));
            u32x2 st;
            st.x = pack2(gv.x, gv.y); st.y = pack2(gv.z, gv.w);
            *(u32x2*)&gate[idx] = st;              // gate stored bf16
          }
        } else {
          u32x2 st;
          st.x = pack2(v.x, v.y); st.y = pack2(v.z, v.w);
          if (oi == 0) *(u32x2*)&kp[idx] = st;
          else         *(u32x2*)&vp[idx] = st;
        }
        acc[j] = f32x4{0.f, 0.f, 0.f, 0.f};
      }
    }
  }
}

// ---------------------------------------------------------------------------
// Kernel 2: fused attention, 1 block per (b, h, q-half), 8 waves x 32 q-rows.
// Swapped QK^T (S^T = K.Q^T) so D-fragments hold 4 CONSECUTIVE k per lane ->
// bias streams load as coalesced float4. NO online max: logits are bounded
// (~|16| worst case; exp2 fits fp32 easily; bf16 precision is scale-free),
// so p = exp2(s*log2e) directly, l just accumulates. PV via shfl_xor(16)
// reassembly with k-slot permutation pi = [0,16,8,24] absorbed into V reads.
// grid=512 -> 2 blocks/CU (146KB LDS), 4 waves/SIMD for latency hiding.
// R2: bias sum (bb+nb+bk) folded into MFMA C-operand -> fewer VALU adds and
// shorter bias-register liveness under the 128-VGPR cap.
// ---------------------------------------------------------------------------
__global__ __launch_bounds__(512, 4) void attn_kernel(
    const unsigned short* __restrict__ qp, const unsigned short* __restrict__ kp,
    const unsigned short* __restrict__ vp,
    const float* __restrict__ bias, const float* __restrict__ nbias,
    const float* __restrict__ bbias,
    unsigned short* __restrict__ wa)
{
  const int bid = blockIdx.x;
  const int h = bid & 7;                    // same-h blocks share an XCD -> nbias L2-hot
  const int qh = (bid >> 3) & 1;
  const int b = bid >> 4;
  const int bh = b * 8 + h;
  const int t = threadIdx.x;
  const int lane = t & 63, wave = t >> 6;
  const int l15 = lane & 15, g = lane >> 4;

  __shared__ unsigned short Klds[512 * 40];  // [k][c], pad 40 (2-way only)
  __shared__ unsigned short Vt[32 * 520];    // V^T [c][k], pad 520

  { // stage K rows + transposed V (512 threads, one k-row each)
    const int row = t;
    const u32x4* ks = (const u32x4*)&kp[((size_t)bh * 512 + row) * 32];
    u32x4 k0 = ks[0], k1 = ks[1], k2 = ks[2], k3 = ks[3];
    *(u32x4*)&Klds[row * 40 + 0]  = k0;
    *(u32x4*)&Klds[row * 40 + 8]  = k1;
    *(u32x4*)&Klds[row * 40 + 16] = k2;
    *(u32x4*)&Klds[row * 40 + 24] = k3;
    const u32x4* vs = (const u32x4*)&vp[((size_t)bh * 512 + row) * 32];
#pragma unroll
    for (int cc = 0; cc < 4; ++cc) {
      u32x4 vv = vs[cc];
      unsigned int dw0 = vv.x, dw1 = vv.y, dw2 = vv.z, dw3 = vv.w;
      const int c = cc * 8;
      Vt[(c + 0) * 520 + row] = (unsigned short)(dw0 & 0xffff);
      Vt[(c + 1) * 520 + row] = (unsigned short)(dw0 >> 16);
      Vt[(c + 2) * 520 + row] = (unsigned short)(dw1 & 0xffff);
      Vt[(c + 3) * 520 + row] = (unsigned short)(dw1 >> 16);
      Vt[(c + 4) * 520 + row] = (unsigned short)(dw2 & 0xffff);
      Vt[(c + 5) * 520 + row] = (unsigned short)(dw2 >> 16);
      Vt[(c + 6) * 520 + row] = (unsigned short)(dw3 & 0xffff);
      Vt[(c + 7) * 520 + row] = (unsigned short)(dw3 >> 16);
    }
  }

  const int qbase = qh * 256 + wave * 32;
  short8 qf[2];                              // Q as B-operand: col q=l15, c=8g+j
#pragma unroll
  for (int qt = 0; qt < 2; ++qt)
    qf[qt] = __builtin_bit_cast(short8,
        *(const u32x4*)&qp[((size_t)bh * 512 + qbase + qt * 16 + l15) * 32 + 8 * g]);

  const float* bbp = bbias + (size_t)bh * 512 * 512;
  const float* nbp = nbias + (size_t)h * 512 * 512;
  const float* bkp = bias + (size_t)b * 512;

  f32x4 acc[2][2];
#pragma unroll
  for (int ct = 0; ct < 2; ++ct)
#pragma unroll
    for (int qt = 0; qt < 2; ++qt) acc[ct][qt] = f32x4{0.f, 0.f, 0.f, 0.f};
  float l_r[2] = {0.f, 0.f};

  __syncthreads();

  const int pib = ((g & 1) << 4) | ((g >> 1) << 3);  // pi = [0,16,8,24]
  const bool godd = (g & 1) != 0;

  for (int kt = 0; kt < 16; ++kt) {
    const int k0 = kt * 32;
    short8 kf0 = __builtin_bit_cast(short8, *(const u32x4*)&Klds[(k0 + l15) * 40 + 8 * g]);
    short8 kf1 = __builtin_bit_cast(short8, *(const u32x4*)&Klds[(k0 + 16 + l15) * 40 + 8 * g]);
    short8 vf0 = __builtin_bit_cast(short8, *(const u32x4*)&Vt[l15 * 520 + k0 + pib]);
    short8 vf1 = __builtin_bit_cast(short8, *(const u32x4*)&Vt[(16 + l15) * 520 + k0 + pib]);
    f32x4 bk0 = *(const f32x4*)&bkp[k0 + 4 * g];
    f32x4 bk1 = *(const f32x4*)&bkp[k0 + 16 + 4 * g];
#pragma unroll
    for (int qt = 0; qt < 2; ++qt) {
      const int q = qbase + qt * 16 + l15;
      const float* bq = &bbp[(size_t)q * 512 + k0 + 4 * g];
      const float* nq = &nbp[(size_t)q * 512 + k0 + 4 * g];
      f32x4 bb0 = *(const f32x4*)bq;
      f32x4 bb1 = *(const f32x4*)(bq + 16);
      f32x4 nb0 = *(const f32x4*)nq;
      f32x4 nb1 = *(const f32x4*)(nq + 16);
      f32x4 c0 = (bb0 + nb0) + bk0;          // bias folded into MFMA C-op
      f32x4 c1 = (bb1 + nb1) + bk1;
      f32x4 s0 = mfma16(kf0, qf[qt], c0);    // S^T: row k=4g+r, col q=l15
      f32x4 s1 = mfma16(kf1, qf[qt], c1);
      f32x4 p0, p1;                          // no max subtraction (bounded logits)
      p0.x = exp2f(s0.x * L2E); p0.y = exp2f(s0.y * L2E);
      p0.z = exp2f(s0.z * L2E); p0.w = exp2f(s0.w * L2E);
      p1.x = exp2f(s1.x * L2E); p1.y = exp2f(s1.y * L2E);
      p1.z = exp2f(s1.z * L2E); p1.w = exp2f(s1.w * L2E);
      float sum8 = (p0.x + p0.y) + (p0.z + p0.w) + (p1.x + p1.y) + (p1.z + p1.w);
      sum8 += __shfl_xor(sum8, 16, 64);
      sum8 += __shfl_xor(sum8, 32, 64);
      l_r[qt] += sum8;
      // assemble P^T B-fragment (col q=l15, k-slots permuted by pi)
      unsigned int d0 = pack2(p0.x, p0.y), d1 = pack2(p0.z, p0.w);
      unsigned int e0 = pack2(p1.x, p1.y), e1 = pack2(p1.z, p1.w);
      unsigned int pd0 = __shfl_xor(d0, 16, 64), pd1 = __shfl_xor(d1, 16, 64);
      unsigned int pe0 = __shfl_xor(e0, 16, 64), pe1 = __shfl_xor(e1, 16, 64);
      u32x4 pfu;
      pfu.x = godd ? pe0 : d0;
      pfu.y = godd ? pe1 : d1;
      pfu.z = godd ? e0 : pd0;
      pfu.w = godd ? e1 : pd1;
      short8 pf = __builtin_bit_cast(short8, pfu);
      acc[0][qt] = mfma16(vf0, pf, acc[0][qt]);   // wa^T: row c, col q
      acc[1][qt] = mfma16(vf1, pf, acc[1][qt]);
    }
  }

  // epilogue: wa[b,h,q,c] bf16; lane holds c = ct*16+4g+r (contiguous 4)
  unsigned short* wab = wa + (size_t)bh * 512 * 32;
#pragma unroll
  for (int qt = 0; qt < 2; ++qt) {
    const float rl = 1.0f / l_r[qt];
    const int q = qbase + qt * 16 + l15;
#pragma unroll
    for (int ct = 0; ct < 2; ++ct) {
      f32x4 v = acc[ct][qt];
      u32x2 st;
      st.x = pack2(v.x * rl, v.y * rl);
      st.y = pack2(v.z * rl, v.w * rl);
      *(u32x2*)&wab[q * 32 + ct * 16 + 4 * g] = st;
    }
  }
}

// ---------------------------------------------------------------------------
// Kernel 3: out[b,q,o] = sum_hc wa*gate * W3[hc][o] + output_b[o]
// R2: 32 rows/block (grid 512 -> 2 blocks/CU, 2 waves/SIMD), n-dim split
// across wave pairs (acc[8]); gate read as bf16. W3 dbuf, act prefetched.
// ---------------------------------------------------------------------------
__global__ __launch_bounds__(256, 2) void outp_kernel(
    const unsigned short* __restrict__ wa, const unsigned short* __restrict__ gate,
    const unsigned short* __restrict__ wt3, const float* __restrict__ out_b,
    float* __restrict__ out)
{
  const int r0 = blockIdx.x * 32;
  const int t = threadIdx.x;
  const int lane = t & 63, wave = t >> 6;
  const int l15 = lane & 15, g = lane >> 4;
  const int stripe = wave & 1, half = wave >> 1;
  __shared__ unsigned short Wlds[2][256 * 40];

  const int grow = r0 + stripe * 16 + l15;   // B-col -> data row (b*512+q)
  const int b = grow >> 9, q = grow & 511;

  { // prologue: W3 slice 0 -> buf 0 (256 threads, one n-row each)
    const u32x4* wsrc = (const u32x4*)&wt3[(size_t)t * 256];
    u32x4 a = wsrc[0], bb = wsrc[1], c = wsrc[2], d = wsrc[3];
    *(u32x4*)&Wlds[0][t * 40 + 0]  = a;
    *(u32x4*)&Wlds[0][t * 40 + 8]  = bb;
    *(u32x4*)&Wlds[0][t * 40 + 16] = c;
    *(u32x4*)&Wlds[0][t * 40 + 24] = d;
  }
  // prologue: activation slice 0 (h = 0)
  size_t aidx = ((size_t)(b * 8 + 0) * 512 + q) * 32 + 8 * g;
  u32x4 cwv = *(const u32x4*)&wa[aidx];
  u32x4 cgv = *(const u32x4*)&gate[aidx];

  f32x4 acc[8];
#pragma unroll
  for (int j = 0; j < 8; ++j) acc[j] = f32x4{0.f, 0.f, 0.f, 0.f};

#pragma unroll
  for (int s = 0; s < 8; ++s) {              // slice s: h = s, c = 8g..8g+7
    const int p = s & 1;
    __syncthreads();
    u32x4 nw0, nw1, nw2, nw3, nwv, ngv;
    if (s < 7) {
      const u32x4* wsrc = (const u32x4*)&wt3[(size_t)t * 256 + (s + 1) * 32];
      nw0 = wsrc[0]; nw1 = wsrc[1]; nw2 = wsrc[2]; nw3 = wsrc[3];
      const size_t na = ((size_t)(b * 8 + s + 1) * 512 + q) * 32 + 8 * g;
      nwv = *(const u32x4*)&wa[na];
      ngv = *(const u32x4*)&gate[na];
    }
    // build gated-activation B-fragment from current regs (both bf16)
    float f0 = b2f(cwv.x & 0xffff) * b2f(cgv.x & 0xffff);
    float f1 = b2f(cwv.x >> 16)    * b2f(cgv.x >> 16);
    float f2 = b2f(cwv.y & 0xffff) * b2f(cgv.y & 0xffff);
    float f3 = b2f(cwv.y >> 16)    * b2f(cgv.y >> 16);
    float f4 = b2f(cwv.z & 0xffff) * b2f(cgv.z & 0xffff);
    float f5 = b2f(cwv.z >> 16)    * b2f(cgv.z >> 16);
    float f6 = b2f(cwv.w & 0xffff) * b2f(cgv.w & 0xffff);
    float f7 = b2f(cwv.w >> 16)    * b2f(cgv.w >> 16);
    u32x4 au;
    au.x = pack2(f0, f1); au.y = pack2(f2, f3);
    au.z = pack2(f4, f5); au.w = pack2(f6, f7);
    short8 af = __builtin_bit_cast(short8, au);
#pragma unroll
    for (int j = 0; j < 8; ++j) {
      short8 wf = __builtin_bit_cast(short8,
          *(const u32x4*)&Wlds[p][((half * 8 + j) * 16 + l15) * 40 + 8 * g]);
      acc[j] = mfma16(wf, af, acc[j]);       // D: row=o(4g+r), col=q(l15)
    }
    if (s < 7) {
      *(u32x4*)&Wlds[p ^ 1][t * 40 + 0]  = nw0;
      *(u32x4*)&Wlds[p ^ 1][t * 40 + 8]  = nw1;
      *(u32x4*)&Wlds[p ^ 1][t * 40 + 16] = nw2;
      *(u32x4*)&Wlds[p ^ 1][t * 40 + 24] = nw3;
      cwv = nwv; cgv = ngv;
    }
  }
#pragma unroll
  for (int j = 0; j < 8; ++j) {
    const int o0 = (half * 8 + j) * 16 + 4 * g;  // 4 consecutive o per lane
    f32x4 ob4 = *(const f32x4*)&out_b[o0];
    f32x4 v = acc[j] + ob4;
    *(f32x4*)&out[(size_t)grow * 256 + o0] = v;
  }
}

// ---------------------------------------------------------------------------
extern "C" void kernel_launch(void* const* d_in, const int* in_sizes, int n_in,
                              void* d_out, int out_size, void* d_ws, size_t ws_size,
                              hipStream_t stream)
{
  const float* q_data   = (const float*)d_in[0];
  const float* m_data   = (const float*)d_in[1];
  const float* bias     = (const float*)d_in[2];
  const float* nbb      = (const float*)d_in[3];
  const float* bbb      = (const float*)d_in[4];
  const float* query_w  = (const float*)d_in[5];
  const float* key_w    = (const float*)d_in[6];
  const float* value_w  = (const float*)d_in[7];
  const float* gating_w = (const float*)d_in[8];
  const float* gating_b = (const float*)d_in[9];
  const float* output_w = (const float*)d_in[10];
  const float* output_b = (const float*)d_in[11];
  float* out = (float*)d_out;

  const size_t QP_B   = (size_t)32 * 8 * 512 * 32 * 2;  // 8 MiB bf16 [B,H,S,C]
  const size_t GATE_B = (size_t)32 * 8 * 512 * 32 * 2;  // 8 MiB bf16
  const size_t WT_B   = (size_t)256 * 256 * 2;

  char* ws = (char*)d_ws;
  unsigned short* qp  = (unsigned short*)(ws);
  unsigned short* kp  = (unsigned short*)(ws + QP_B);
  unsigned short* vp  = (unsigned short*)(ws + 2 * QP_B);
  unsigned short* wab = (unsigned short*)(ws + 3 * QP_B);
  unsigned short* gat = (unsigned short*)(ws + 4 * QP_B);
  unsigned short* wtq = (unsigned short*)(ws + 4 * QP_B + GATE_B);
  unsigned short* wtk = (unsigned short*)(ws + 4 * QP_B + GATE_B + WT_B);
  unsigned short* wtv = (unsigned short*)(ws + 4 * QP_B + GATE_B + 2 * WT_B);
  unsigned short* wtg = (unsigned short*)(ws + 4 * QP_B + GATE_B + 3 * WT_B);
  unsigned short* wt3 = (unsigned short*)(ws + 4 * QP_B + GATE_B + 4 * WT_B);
  const size_t need = 4 * QP_B + GATE_B + 5 * WT_B;
  if (ws_size < need) return;  // fail loudly (out stays poisoned)

  hipLaunchKernelGGL(wtrans_kernel, dim3(80), dim3(256), 0, stream,
                     query_w, key_w, value_w, gating_w, output_w,
                     wtq, wtk, wtv, wtg, wt3);
  hipLaunchKernelGGL(proj_kernel, dim3(512), dim3(512), 0, stream,
                     q_data, m_data, wtq, wtk, wtv, wtg, gating_b,
                     qp, kp, vp, gat);
  hipLaunchKernelGGL(attn_kernel, dim3(512), dim3(512), 0, stream,
                     qp, kp, vp, bias, nbb, bbb, wab);
  hipLaunchKernelGGL(outp_kernel, dim3(512), dim3(256), 0, stream,
                     wab, gat, wt3, output_b, out);
}

// Round 3
// 133.035 us; speedup vs baseline: 1.5712x; 1.0202x over previous
//
#include <hip/hip_runtime.h>
#include <cstdint>
#include <cstddef>

// ---------------------------------------------------------------------------
// Gated attention (AlphaFold-style), MI355X / gfx950.
// B=32, Q=K=512, A=256, H=8, C=32, O=256.  All inputs fp32, output fp32.
// Internally bf16 MFMA (threshold is ~2% of max|ref| -> plenty of margin).
// R3: attn instruction diet + latency pipeline:
//   - pack2 -> v_cvt_pk_bf16_f32 (1 instr vs ~10 bit-twiddle VALU)
//   - log2e folded into qp scale + bias fma chain (no post-MFMA muls)
//   - bias row (b,1,1,K) pre-scaled, staged in LDS
//   - l-reduce deferred to epilogue (no per-kt cross-lane shfl)
//   - bias loads software-pipelined half-a-kt ahead (latency cover)
// ---------------------------------------------------------------------------

typedef __attribute__((ext_vector_type(8))) short short8;   // 8 x bf16 (raw bits)
typedef __attribute__((ext_vector_type(4))) float f32x4;
typedef __attribute__((ext_vector_type(4))) unsigned int u32x4;
typedef __attribute__((ext_vector_type(2))) unsigned int u32x2;

#define DEVFN static __device__ __forceinline__
#define L2E 1.4426950408889634f

DEVFN float b2f(unsigned int bits16) {        // bf16 bits -> fp32
  return __builtin_bit_cast(float, bits16 << 16);
}
DEVFN unsigned int pack2(float a, float b) {  // two bf16 (RNE) in one dword
  unsigned int r;
  asm("v_cvt_pk_bf16_f32 %0, %1, %2" : "=v"(r) : "v"(a), "v"(b));
  return r;
}
DEVFN f32x4 mfma16(short8 a, short8 b, f32x4 c) {
  return __builtin_amdgcn_mfma_f32_16x16x32_bf16(a, b, c, 0, 0, 0);
}
// MFMA 16x16x32 layouts (gfx950, per verified guide):
//  A: row = lane&15,           k = 8*(lane>>4)+j   (j=0..7)
//  B: col = lane&15,           k = 8*(lane>>4)+j
//  D: col = lane&15,           row = 4*(lane>>4)+r (r=0..3)

// ---------------------------------------------------------------------------
// Kernel 0: transpose 5 weight matrices [256][256] fp32 -> bf16 W^T [n][a]
// ---------------------------------------------------------------------------
__global__ __launch_bounds__(256) void wtrans_kernel(
    const float* __restrict__ qw, const float* __restrict__ kw,
    const float* __restrict__ vw, const float* __restrict__ gw,
    const float* __restrict__ ow,
    unsigned short* __restrict__ wtq, unsigned short* __restrict__ wtk,
    unsigned short* __restrict__ wtv, unsigned short* __restrict__ wtg,
    unsigned short* __restrict__ wt3)
{
  const int matid = blockIdx.x >> 4;
  const int tile  = blockIdx.x & 15;
  const float* src = (matid == 0) ? qw : (matid == 1) ? kw : (matid == 2) ? vw
                   : (matid == 3) ? gw : ow;
  unsigned short* dst = (matid == 0) ? wtq : (matid == 1) ? wtk : (matid == 2) ? wtv
                      : (matid == 3) ? wtg : wt3;
  const int tr = (tile >> 2) * 64, tc = (tile & 3) * 64;
  __shared__ unsigned short T[64 * 72];
  const int t = threadIdx.x;
  {
    const int row = t >> 2, cb = (t & 3) * 16;
#pragma unroll
    for (int ii = 0; ii < 4; ++ii) {
      f32x4 v = *(const f32x4*)&src[(size_t)(tr + row) * 256 + tc + cb + ii * 4];
      u32x2 p; p.x = pack2(v.x, v.y); p.y = pack2(v.z, v.w);
      *(u32x2*)&T[row * 72 + cb + ii * 4] = p;
    }
  }
  __syncthreads();
  {
    const int c0 = t >> 2, rb = (t & 3) * 16;
    unsigned short vals[16];
#pragma unroll
    for (int m = 0; m < 16; ++m) vals[m] = T[(rb + m) * 72 + c0];
    u32x4 s0, s1;
    s0.x = (unsigned)vals[0]  | ((unsigned)vals[1]  << 16);
    s0.y = (unsigned)vals[2]  | ((unsigned)vals[3]  << 16);
    s0.z = (unsigned)vals[4]  | ((unsigned)vals[5]  << 16);
    s0.w = (unsigned)vals[6]  | ((unsigned)vals[7]  << 16);
    s1.x = (unsigned)vals[8]  | ((unsigned)vals[9]  << 16);
    s1.y = (unsigned)vals[10] | ((unsigned)vals[11] << 16);
    s1.z = (unsigned)vals[12] | ((unsigned)vals[13] << 16);
    s1.w = (unsigned)vals[14] | ((unsigned)vals[15] << 16);
    unsigned short* dp = &dst[(size_t)(tc + c0) * 256 + tr + rb];
    *(u32x4*)dp = s0;
    *(u32x4*)(dp + 8) = s1;
  }
}

// ---------------------------------------------------------------------------
// Kernel 1: projections. blocks 0..255: q_data -> q(bf16,scaled) + gate(bf16)
//           blocks 256..511: m_data -> k(bf16) + v(bf16).
// Outputs laid out [B,H,S,C] (contiguous per (b,h) slice).
// qp is scaled by keyscale*log2e (log2e folded out of the attn hot loop).
// ---------------------------------------------------------------------------
__global__ __launch_bounds__(512, 4) void proj_kernel(
    const float* __restrict__ q_data, const float* __restrict__ m_data,
    const unsigned short* __restrict__ wtq, const unsigned short* __restrict__ wtk,
    const unsigned short* __restrict__ wtv, const unsigned short* __restrict__ wtg,
    const float* __restrict__ gating_b,
    unsigned short* __restrict__ qp, unsigned short* __restrict__ kp,
    unsigned short* __restrict__ vp, unsigned short* __restrict__ gate)
{
  const int bid = blockIdx.x;
  const bool mside = bid >= 256;
  const int r0 = (mside ? bid - 256 : bid) * 64;
  const float* inp = mside ? m_data : q_data;
  __shared__ unsigned short Alds[64 * 264];       // 64 rows x 256 a, pad 264
  __shared__ unsigned short Wlds[2][256 * 40];    // dbuf: 256 n x 32 a-slice
  const int t = threadIdx.x;
  const int lane = t & 63, wave = t >> 6;
  const int l15 = lane & 15, g = lane >> 4;
  const int stripe = wave & 3, nhalf = wave >> 2;

  { // stage A tile as bf16: 512 threads x 32 floats
    const int row = t >> 3, cb = (t & 7) * 32;
    const float* ip = &inp[(size_t)(r0 + row) * 256 + cb];
#pragma unroll
    for (int i = 0; i < 4; ++i) {
      f32x4 a0 = *(const f32x4*)&ip[i * 8];
      f32x4 a1 = *(const f32x4*)&ip[i * 8 + 4];
      u32x4 pk;
      pk.x = pack2(a0.x, a0.y); pk.y = pack2(a0.z, a0.w);
      pk.z = pack2(a1.x, a1.y); pk.w = pack2(a1.z, a1.w);
      *(u32x4*)&Alds[row * 264 + cb + i * 8] = pk;
    }
  }

  const unsigned short* wt0 = mside ? wtk : wtq;
  const unsigned short* wt1 = mside ? wtv : wtg;
  const int wrow = t & 255, whalf = t >> 8;       // W staging: 2 threads/row

  { // prologue: W slice 0 -> buf 0
    const u32x4* wsrc = (const u32x4*)&wt0[(size_t)wrow * 256 + whalf * 16];
    u32x4 a = wsrc[0], b = wsrc[1];
    *(u32x4*)&Wlds[0][wrow * 40 + whalf * 16 + 0] = a;
    *(u32x4*)&Wlds[0][wrow * 40 + whalf * 16 + 8] = b;
  }

  f32x4 acc[8];
#pragma unroll
  for (int j = 0; j < 8; ++j) acc[j] = f32x4{0.f, 0.f, 0.f, 0.f};

  const int arow = (stripe * 16 + l15) * 264 + 8 * g;
  const int grow = r0 + stripe * 16 + l15;        // B-col -> data row (b*512+q)
  const int ob = grow >> 9, oq = grow & 511;

#pragma unroll
  for (int s = 0; s < 16; ++s) {                  // s = oi*8 + ks
    const int p = s & 1;
    __syncthreads();                               // buf p ready; buf p^1 free
    u32x4 nw0, nw1;
    if (s < 15) {                                  // issue next-slice W load
      const unsigned short* wt = (s + 1 < 8) ? wt0 : wt1;
      const u32x4* wsrc =
          (const u32x4*)&wt[(size_t)wrow * 256 + ((s + 1) & 7) * 32 + whalf * 16];
      nw0 = wsrc[0]; nw1 = wsrc[1];
    }
    const int ks = s & 7;
    short8 bf = __builtin_bit_cast(short8, *(const u32x4*)&Alds[arow + ks * 32]);
#pragma unroll
    for (int j = 0; j < 8; ++j) {
      short8 wf = __builtin_bit_cast(short8,
          *(const u32x4*)&Wlds[p][((nhalf * 8 + j) * 16 + l15) * 40 + 8 * g]);
      acc[j] = mfma16(wf, bf, acc[j]);             // D: row=n(4g+r), col=q(l15)
    }
    if (s < 15) {
      *(u32x4*)&Wlds[p ^ 1][wrow * 40 + whalf * 16 + 0] = nw0;
      *(u32x4*)&Wlds[p ^ 1][wrow * 40 + whalf * 16 + 8] = nw1;
    }
    if (s == 7 || s == 15) {                       // epilogue per oi
      const int oi = s >> 3;
      // qp scale: keyscale * log2e (log2e folded into logits)
      const float QS = 0.17677669529663687f * 1.4426950408889634f;
#pragma unroll
      for (int j = 0; j < 8; ++j) {
        const int n0 = (nhalf * 8 + j) * 16 + 4 * g;  // 4 consecutive n / lane
        const int h = n0 >> 5, c0 = n0 & 31;
        const size_t idx = ((size_t)(ob * 8 + h) * 512 + oq) * 32 + c0;
        f32x4 v = acc[j];
        if (!mside) {
          if (oi == 0) {
            u32x2 st;
            st.x = pack2(v.x * QS, v.y * QS);
            st.y = pack2(v.z * QS, v.w * QS);
            *(u32x2*)&qp[idx] = st;
          } else {
            f32x4 gb = *(const f32x4*)&gating_b[n0];
            f32x4 gv;
            gv.x = 1.0f / (1.0f + exp2f(-(v.x + gb.x) * L2E));
            gv.y = 1.0f / (1.0f + exp2f(-(v.y + gb.y) * L2E));
            gv.z = 1.0f / (1.0f + exp2f(-(v.z + gb.z) * L2E));
            gv.w = 1.0f / (1.0f + exp2f(-(v.w + gb.w) * L2E));
            u32x2 st;
            st.x = pack2(gv.x, gv.y); st.y = pack2(gv.z, gv.w);
            *(u32x2*)&gate[idx] = st;              // gate stored bf16
          }
        } else {
          u32x2 st;
          st.x = pack2(v.x, v.y); st.y = pack2(v.z, v.w);
          if (oi == 0) *(u32x2*)&kp[idx] = st;
          else         *(u32x2*)&vp[idx] = st;
        }
        acc[j] = f32x4{0.f, 0.f, 0.f, 0.f};
      }
    }
  }
}

// ---------------------------------------------------------------------------
// Kernel 2: fused attention, 1 block per (b, h, q-half), 8 waves x 32 q-rows.
// Swapped QK^T (S^T = K.Q^T); logits already carry log2e (qp pre-scaled;
// biases scaled via fma chain; bias row staged pre-scaled in LDS), so
// p = exp2(s) directly. l accumulates per-lane, reduced once in epilogue.
// Bias loads pipelined half-a-kt ahead: qt1 loads issue before qt0 compute,
// kt+1/qt0 loads issue before qt1 compute -> each load covered by ~1 compute
// stage per wave, x4 waves/SIMD TLP.
// ---------------------------------------------------------------------------
__global__ __launch_bounds__(512, 4) void attn_kernel(
    const unsigned short* __restrict__ qp, const unsigned short* __restrict__ kp,
    const unsigned short* __restrict__ vp,
    const float* __restrict__ bias, const float* __restrict__ nbias,
    const float* __restrict__ bbias,
    unsigned short* __restrict__ wa)
{
  const int bid = blockIdx.x;
  const int h = bid & 7;                    // same-h blocks share an XCD -> nbias L2-hot
  const int qh = (bid >> 3) & 1;
  const int b = bid >> 4;
  const int bh = b * 8 + h;
  const int t = threadIdx.x;
  const int lane = t & 63, wave = t >> 6;
  const int l15 = lane & 15, g = lane >> 4;

  __shared__ unsigned short Klds[512 * 40];  // [k][c], pad 40 (2-way only)
  __shared__ unsigned short Vt[32 * 520];    // V^T [c][k], pad 520
  __shared__ float Bk[512];                  // bias row * log2e

  { // stage K rows + transposed V (512 threads, one k-row each)
    const int row = t;
    const u32x4* ks = (const u32x4*)&kp[((size_t)bh * 512 + row) * 32];
    u32x4 k0 = ks[0], k1 = ks[1], k2 = ks[2], k3 = ks[3];
    *(u32x4*)&Klds[row * 40 + 0]  = k0;
    *(u32x4*)&Klds[row * 40 + 8]  = k1;
    *(u32x4*)&Klds[row * 40 + 16] = k2;
    *(u32x4*)&Klds[row * 40 + 24] = k3;
    const u32x4* vs = (const u32x4*)&vp[((size_t)bh * 512 + row) * 32];
#pragma unroll
    for (int cc = 0; cc < 4; ++cc) {
      u32x4 vv = vs[cc];
      unsigned int dw0 = vv.x, dw1 = vv.y, dw2 = vv.z, dw3 = vv.w;
      const int c = cc * 8;
      Vt[(c + 0) * 520 + row] = (unsigned short)(dw0 & 0xffff);
      Vt[(c + 1) * 520 + row] = (unsigned short)(dw0 >> 16);
      Vt[(c + 2) * 520 + row] = (unsigned short)(dw1 & 0xffff);
      Vt[(c + 3) * 520 + row] = (unsigned short)(dw1 >> 16);
      Vt[(c + 4) * 520 + row] = (unsigned short)(dw2 & 0xffff);
      Vt[(c + 5) * 520 + row] = (unsigned short)(dw2 >> 16);
      Vt[(c + 6) * 520 + row] = (unsigned short)(dw3 & 0xffff);
      Vt[(c + 7) * 520 + row] = (unsigned short)(dw3 >> 16);
    }
    if (t < 128) {                           // stage bias row, pre-scaled
      f32x4 bv = *(const f32x4*)&bias[(size_t)b * 512 + t * 4];
      bv.x *= L2E; bv.y *= L2E; bv.z *= L2E; bv.w *= L2E;
      *(f32x4*)&Bk[t * 4] = bv;
    }
  }

  const int qbase = qh * 256 + wave * 32;
  short8 qf[2];                              // Q as B-operand: col q=l15, c=8g+j
#pragma unroll
  for (int qt = 0; qt < 2; ++qt)
    qf[qt] = __builtin_bit_cast(short8,
        *(const u32x4*)&qp[((size_t)bh * 512 + qbase + qt * 16 + l15) * 32 + 8 * g]);

  // per-lane fixed-row base pointers for the two bias streams
  const float* b0p = bbias + (size_t)bh * 512 * 512 + (size_t)(qbase + l15) * 512 + 4 * g;
  const float* b1p = b0p + 16 * 512;
  const float* n0p = nbias + (size_t)h * 512 * 512 + (size_t)(qbase + l15) * 512 + 4 * g;
  const float* n1p = n0p + 16 * 512;

  f32x4 acc[2][2];
#pragma unroll
  for (int ct = 0; ct < 2; ++ct)
#pragma unroll
    for (int qt = 0; qt < 2; ++qt) acc[ct][qt] = f32x4{0.f, 0.f, 0.f, 0.f};
  float l_part[2] = {0.f, 0.f};

  // prologue bias loads (kt=0, qt=0) — before the barrier for extra cover
  f32x4 Abb0 = *(const f32x4*)(b0p);
  f32x4 Abb1 = *(const f32x4*)(b0p + 16);
  f32x4 Anb0 = *(const f32x4*)(n0p);
  f32x4 Anb1 = *(const f32x4*)(n0p + 16);

  __syncthreads();

  const int pib = ((g & 1) << 4) | ((g >> 1) << 3);  // pi = [0,16,8,24]
  const bool godd = (g & 1) != 0;

  for (int kt = 0; kt < 16; ++kt) {
    const int k0 = kt * 32;
    short8 kf0 = __builtin_bit_cast(short8, *(const u32x4*)&Klds[(k0 + l15) * 40 + 8 * g]);
    short8 kf1 = __builtin_bit_cast(short8, *(const u32x4*)&Klds[(k0 + 16 + l15) * 40 + 8 * g]);
    short8 vf0 = __builtin_bit_cast(short8, *(const u32x4*)&Vt[l15 * 520 + k0 + pib]);
    short8 vf1 = __builtin_bit_cast(short8, *(const u32x4*)&Vt[(16 + l15) * 520 + k0 + pib]);
    f32x4 bks0 = *(const f32x4*)&Bk[k0 + 4 * g];
    f32x4 bks1 = *(const f32x4*)&Bk[k0 + 16 + 4 * g];
    // issue qt=1 bias loads now; consumed after qt=0 compute
    f32x4 Bbb0 = *(const f32x4*)(b1p + k0);
    f32x4 Bbb1 = *(const f32x4*)(b1p + k0 + 16);
    f32x4 Bnb0 = *(const f32x4*)(n1p + k0);
    f32x4 Bnb1 = *(const f32x4*)(n1p + k0 + 16);

#pragma unroll
    for (int qt = 0; qt < 2; ++qt) {
      f32x4 bb0, bb1, nb0, nb1;
      if (qt == 0) { bb0 = Abb0; bb1 = Abb1; nb0 = Anb0; nb1 = Anb1; }
      else         { bb0 = Bbb0; bb1 = Bbb1; nb0 = Bnb0; nb1 = Bnb1; }
      // biases * log2e via fma chain into MFMA C-operand
      f32x4 c0 = bb0 * L2E + (nb0 * L2E + bks0);
      f32x4 c1 = bb1 * L2E + (nb1 * L2E + bks1);
      f32x4 s0 = mfma16(kf0, qf[qt], c0);    // S^T: row k=4g+r, col q=l15
      f32x4 s1 = mfma16(kf1, qf[qt], c1);
      if (qt == 0 && kt < 15) {              // prefetch (kt+1, qt=0)
        Abb0 = *(const f32x4*)(b0p + k0 + 32);
        Abb1 = *(const f32x4*)(b0p + k0 + 48);
        Anb0 = *(const f32x4*)(n0p + k0 + 32);
        Anb1 = *(const f32x4*)(n0p + k0 + 48);
      }
      f32x4 p0, p1;                          // logits carry log2e -> exp2
      p0.x = exp2f(s0.x); p0.y = exp2f(s0.y);
      p0.z = exp2f(s0.z); p0.w = exp2f(s0.w);
      p1.x = exp2f(s1.x); p1.y = exp2f(s1.y);
      p1.z = exp2f(s1.z); p1.w = exp2f(s1.w);
      l_part[qt] += ((p0.x + p0.y) + (p0.z + p0.w)) +
                    ((p1.x + p1.y) + (p1.z + p1.w));
      // assemble P^T B-fragment (col q=l15, k-slots permuted by pi)
      unsigned int d0 = pack2(p0.x, p0.y), d1 = pack2(p0.z, p0.w);
      unsigned int e0 = pack2(p1.x, p1.y), e1 = pack2(p1.z, p1.w);
      unsigned int pd0 = __shfl_xor(d0, 16, 64), pd1 = __shfl_xor(d1, 16, 64);
      unsigned int pe0 = __shfl_xor(e0, 16, 64), pe1 = __shfl_xor(e1, 16, 64);
      u32x4 pfu;
      pfu.x = godd ? pe0 : d0;
      pfu.y = godd ? pe1 : d1;
      pfu.z = godd ? e0 : pd0;
      pfu.w = godd ? e1 : pd1;
      short8 pf = __builtin_bit_cast(short8, pfu);
      acc[0][qt] = mfma16(vf0, pf, acc[0][qt]);   // wa^T: row c, col q
      acc[1][qt] = mfma16(vf1, pf, acc[1][qt]);
    }
  }

  // epilogue: reduce l across g-groups (same l15 column), then store wa
  unsigned short* wab = wa + (size_t)bh * 512 * 32;
#pragma unroll
  for (int qt = 0; qt < 2; ++qt) {
    float l = l_part[qt];
    l += __shfl_xor(l, 16, 64);
    l += __shfl_xor(l, 32, 64);
    const float rl = 1.0f / l;
    const int q = qbase + qt * 16 + l15;
#pragma unroll
    for (int ct = 0; ct < 2; ++ct) {
      f32x4 v = acc[ct][qt];
      u32x2 st;
      st.x = pack2(v.x * rl, v.y * rl);
      st.y = pack2(v.z * rl, v.w * rl);
      *(u32x2*)&wab[q * 32 + ct * 16 + 4 * g] = st;
    }
  }
}

// ---------------------------------------------------------------------------
// Kernel 3: out[b,q,o] = sum_hc wa*gate * W3[hc][o] + output_b[o]
// 32 rows/block (grid 512 -> 2 blocks/CU), n-split across wave pairs;
// gate read bf16; W3 dbuf; act prefetched; cvt_pk packs.
// ---------------------------------------------------------------------------
__global__ __launch_bounds__(256, 2) void outp_kernel(
    const unsigned short* __restrict__ wa, const unsigned short* __restrict__ gate,
    const unsigned short* __restrict__ wt3, const float* __restrict__ out_b,
    float* __restrict__ out)
{
  const int r0 = blockIdx.x * 32;
  const int t = threadIdx.x;
  const int lane = t & 63, wave = t >> 6;
  const int l15 = lane & 15, g = lane >> 4;
  const int stripe = wave & 1, half = wave >> 1;
  __shared__ unsigned short Wlds[2][256 * 40];

  const int grow = r0 + stripe * 16 + l15;   // B-col -> data row (b*512+q)
  const int b = grow >> 9, q = grow & 511;

  { // prologue: W3 slice 0 -> buf 0 (256 threads, one n-row each)
    const u32x4* wsrc = (const u32x4*)&wt3[(size_t)t * 256];
    u32x4 a = wsrc[0], bb = wsrc[1], c = wsrc[2], d = wsrc[3];
    *(u32x4*)&Wlds[0][t * 40 + 0]  = a;
    *(u32x4*)&Wlds[0][t * 40 + 8]  = bb;
    *(u32x4*)&Wlds[0][t * 40 + 16] = c;
    *(u32x4*)&Wlds[0][t * 40 + 24] = d;
  }
  // prologue: activation slice 0 (h = 0)
  size_t aidx = ((size_t)(b * 8 + 0) * 512 + q) * 32 + 8 * g;
  u32x4 cwv = *(const u32x4*)&wa[aidx];
  u32x4 cgv = *(const u32x4*)&gate[aidx];

  f32x4 acc[8];
#pragma unroll
  for (int j = 0; j < 8; ++j) acc[j] = f32x4{0.f, 0.f, 0.f, 0.f};

#pragma unroll
  for (int s = 0; s < 8; ++s) {              // slice s: h = s, c = 8g..8g+7
    const int p = s & 1;
    __syncthreads();
    u32x4 nw0, nw1, nw2, nw3, nwv, ngv;
    if (s < 7) {
      const u32x4* wsrc = (const u32x4*)&wt3[(size_t)t * 256 + (s + 1) * 32];
      nw0 = wsrc[0]; nw1 = wsrc[1]; nw2 = wsrc[2]; nw3 = wsrc[3];
      const size_t na = ((size_t)(b * 8 + s + 1) * 512 + q) * 32 + 8 * g;
      nwv = *(const u32x4*)&wa[na];
      ngv = *(const u32x4*)&gate[na];
    }
    // build gated-activation B-fragment from current regs (both bf16)
    float f0 = b2f(cwv.x & 0xffff) * b2f(cgv.x & 0xffff);
    float f1 = b2f(cwv.x >> 16)    * b2f(cgv.x >> 16);
    float f2 = b2f(cwv.y & 0xffff) * b2f(cgv.y & 0xffff);
    float f3 = b2f(cwv.y >> 16)    * b2f(cgv.y >> 16);
    float f4 = b2f(cwv.z & 0xffff) * b2f(cgv.z & 0xffff);
    float f5 = b2f(cwv.z >> 16)    * b2f(cgv.z >> 16);
    float f6 = b2f(cwv.w & 0xffff) * b2f(cgv.w & 0xffff);
    float f7 = b2f(cwv.w >> 16)    * b2f(cgv.w >> 16);
    u32x4 au;
    au.x = pack2(f0, f1); au.y = pack2(f2, f3);
    au.z = pack2(f4, f5); au.w = pack2(f6, f7);
    short8 af = __builtin_bit_cast(short8, au);
#pragma unroll
    for (int j = 0; j < 8; ++j) {
      short8 wf = __builtin_bit_cast(short8,
          *(const u32x4*)&Wlds[p][((half * 8 + j) * 16 + l15) * 40 + 8 * g]);
      acc[j] = mfma16(wf, af, acc[j]);       // D: row=o(4g+r), col=q(l15)
    }
    if (s < 7) {
      *(u32x4*)&Wlds[p ^ 1][t * 40 + 0]  = nw0;
      *(u32x4*)&Wlds[p ^ 1][t * 40 + 8]  = nw1;
      *(u32x4*)&Wlds[p ^ 1][t * 40 + 16] = nw2;
      *(u32x4*)&Wlds[p ^ 1][t * 40 + 24] = nw3;
      cwv = nwv; cgv = ngv;
    }
  }
#pragma unroll
  for (int j = 0; j < 8; ++j) {
    const int o0 = (half * 8 + j) * 16 + 4 * g;  // 4 consecutive o per lane
    f32x4 ob4 = *(const f32x4*)&out_b[o0];
    f32x4 v = acc[j] + ob4;
    *(f32x4*)&out[(size_t)grow * 256 + o0] = v;
  }
}

// ---------------------------------------------------------------------------
extern "C" void kernel_launch(void* const* d_in, const int* in_sizes, int n_in,
                              void* d_out, int out_size, void* d_ws, size_t ws_size,
                              hipStream_t stream)
{
  const float* q_data   = (const float*)d_in[0];
  const float* m_data   = (const float*)d_in[1];
  const float* bias     = (const float*)d_in[2];
  const float* nbb      = (const float*)d_in[3];
  const float* bbb      = (const float*)d_in[4];
  const float* query_w  = (const float*)d_in[5];
  const float* key_w    = (const float*)d_in[6];
  const float* value_w  = (const float*)d_in[7];
  const float* gating_w = (const float*)d_in[8];
  const float* gating_b = (const float*)d_in[9];
  const float* output_w = (const float*)d_in[10];
  const float* output_b = (const float*)d_in[11];
  float* out = (float*)d_out;

  const size_t QP_B   = (size_t)32 * 8 * 512 * 32 * 2;  // 8 MiB bf16 [B,H,S,C]
  const size_t GATE_B = (size_t)32 * 8 * 512 * 32 * 2;  // 8 MiB bf16
  const size_t WT_B   = (size_t)256 * 256 * 2;

  char* ws = (char*)d_ws;
  unsigned short* qp  = (unsigned short*)(ws);
  unsigned short* kp  = (unsigned short*)(ws + QP_B);
  unsigned short* vp  = (unsigned short*)(ws + 2 * QP_B);
  unsigned short* wab = (unsigned short*)(ws + 3 * QP_B);
  unsigned short* gat = (unsigned short*)(ws + 4 * QP_B);
  unsigned short* wtq = (unsigned short*)(ws + 4 * QP_B + GATE_B);
  unsigned short* wtk = (unsigned short*)(ws + 4 * QP_B + GATE_B + WT_B);
  unsigned short* wtv = (unsigned short*)(ws + 4 * QP_B + GATE_B + 2 * WT_B);
  unsigned short* wtg = (unsigned short*)(ws + 4 * QP_B + GATE_B + 3 * WT_B);
  unsigned short* wt3 = (unsigned short*)(ws + 4 * QP_B + GATE_B + 4 * WT_B);
  const size_t need = 4 * QP_B + GATE_B + 5 * WT_B;
  if (ws_size < need) return;  // fail loudly (out stays poisoned)

  hipLaunchKernelGGL(wtrans_kernel, dim3(80), dim3(256), 0, stream,
                     query_w, key_w, value_w, gating_w, output_w,
                     wtq, wtk, wtv, wtg, wt3);
  hipLaunchKernelGGL(proj_kernel, dim3(512), dim3(512), 0, stream,
                     q_data, m_data, wtq, wtk, wtv, wtg, gating_b,
                     qp, kp, vp, gat);
  hipLaunchKernelGGL(attn_kernel, dim3(512), dim3(512), 0, stream,
                     qp, kp, vp, bias, nbb, bbb, wab);
  hipLaunchKernelGGL(outp_kernel, dim3(512), dim3(256), 0, stream,
                     wab, gat, wt3, output_b, out);
}